// Round 1
// baseline (954.451 us; speedup 1.0000x reference)
//
#include <hip/hip_runtime.h>
#include <math.h>

#define N 4096
#define D 512
#define TOPK 10
#define TOPK_HALF 5

// ---------------- K init: zero the double accumulator ----------------
__global__ void k_init(double* acc) { acc[0] = 0.0; }

// ---------------- K0: row L2-normalize + rowsq of normalized ----------------
__global__ __launch_bounds__(256) void k_normalize(const float* __restrict__ x,
                                                   float* __restrict__ y,
                                                   float* __restrict__ rowsq) {
  int row = blockIdx.x, tid = threadIdx.x;
  const float* xr = x + (size_t)row * D;
  float v0 = xr[tid], v1 = xr[tid + 256];
  float ss = v0 * v0 + v1 * v1;
  __shared__ float red[4];
  for (int off = 32; off > 0; off >>= 1) ss += __shfl_down(ss, off, 64);
  if ((tid & 63) == 0) red[tid >> 6] = ss;
  __syncthreads();
  float tot = red[0] + red[1] + red[2] + red[3];
  float inv = 1.0f / fmaxf(sqrtf(tot), 1e-12f);
  float y0 = v0 * inv, y1 = v1 * inv;
  float* yr = y + (size_t)row * D;
  yr[tid] = y0; yr[tid + 256] = y1;
  float s2 = y0 * y0 + y1 * y1;
  for (int off = 32; off > 0; off >>= 1) s2 += __shfl_down(s2, off, 64);
  __syncthreads();
  if ((tid & 63) == 0) red[tid >> 6] = s2;
  __syncthreads();
  if (tid == 0) rowsq[row] = red[0] + red[1] + red[2] + red[3];
}

// ---------------- K1: G = X * X^T  (fp32 tiled) ----------------
#define BM 64
#define BN 64
#define BK 32
__global__ __launch_bounds__(256) void k_gram(const float* __restrict__ X,
                                              float* __restrict__ G) {
  __shared__ float As[BK][BM + 4];
  __shared__ float Bs[BK][BN + 4];
  int bx = blockIdx.x, by = blockIdx.y;
  int tid = threadIdx.x;
  int tx = tid & 15, ty = tid >> 4;
  float acc[4][4] = {};
  const float* Arow = X + (size_t)(by * BM) * D;
  const float* Brow = X + (size_t)(bx * BN) * D;
  for (int k0 = 0; k0 < D; k0 += BK) {
#pragma unroll
    for (int l = 0; l < 2; ++l) {
      int id = tid + l * 256;
      int r = id >> 3;
      int c4 = (id & 7) * 4;
      float4 a = *(const float4*)(Arow + (size_t)r * D + k0 + c4);
      As[c4 + 0][r] = a.x; As[c4 + 1][r] = a.y; As[c4 + 2][r] = a.z; As[c4 + 3][r] = a.w;
      float4 b = *(const float4*)(Brow + (size_t)r * D + k0 + c4);
      Bs[c4 + 0][r] = b.x; Bs[c4 + 1][r] = b.y; Bs[c4 + 2][r] = b.z; Bs[c4 + 3][r] = b.w;
    }
    __syncthreads();
#pragma unroll
    for (int k = 0; k < BK; ++k) {
      float a[4], b[4];
#pragma unroll
      for (int u = 0; u < 4; ++u) a[u] = As[k][ty * 4 + u];
#pragma unroll
      for (int u = 0; u < 4; ++u) b[u] = Bs[k][tx * 4 + u];
#pragma unroll
      for (int u = 0; u < 4; ++u)
#pragma unroll
        for (int v = 0; v < 4; ++v)
          acc[u][v] = fmaf(a[u], b[v], acc[u][v]);
    }
    __syncthreads();
  }
#pragma unroll
  for (int u = 0; u < 4; ++u) {
    int gi = by * BM + ty * 4 + u;
    float* Grow = G + (size_t)gi * N + bx * BN + tx * 4;
#pragma unroll
    for (int v = 0; v < 4; ++v) Grow[v] = acc[u][v];
  }
}

// ---------------- K2: row mean of S_raw ----------------
__global__ __launch_bounds__(256) void k_rowmean(const float* __restrict__ Gs,
                                                 const float* __restrict__ rsq,
                                                 float* __restrict__ mean) {
  int i = blockIdx.x, tid = threadIdx.x;
  float rsi = rsq[i];
  const float* row = Gs + (size_t)i * N;
  float s = 0.f;
  for (int j = tid; j < N; j += 256) {
    float sq = rsi + rsq[j] - 2.0f * row[j];
    s += sqrtf(fmaxf(sq, 0.0f));
  }
  __shared__ float red[4];
  for (int off = 32; off > 0; off >>= 1) s += __shfl_down(s, off, 64);
  if ((tid & 63) == 0) red[tid >> 6] = s;
  __syncthreads();
  if (tid == 0) mean[i] = (red[0] + red[1] + red[2] + red[3]) * (1.0f / (float)N);
}

// ---------------- K3: exact top-10 per row with JAX tie-break ----------------
__global__ __launch_bounds__(256) void k_topk(const float* __restrict__ Gt,
                                              const float* __restrict__ rsq,
                                              const int* __restrict__ ids,
                                              int* __restrict__ topk) {
  __shared__ unsigned long long keys[N];       // 32 KB
  __shared__ unsigned long long rbest[256];
  __shared__ int rslot[256];
  int i = blockIdx.x, tid = threadIdx.x;
  float rsi = rsq[i];
  int idi = ids[i];
  const float* row = Gt + (size_t)i * N;
  for (int j = tid; j < N; j += 256) {
    float sq = fmaxf(rsi + rsq[j] - 2.0f * row[j], 0.0f);
    float w = (ids[j] == idi) ? 1.0f : expf(-sq);   // W_P_copy
    unsigned int fb = __float_as_uint(w);           // w > 0 -> monotonic bits
    keys[j] = ((unsigned long long)fb << 32) |
              (unsigned long long)(0xFFFFFFFFu - (unsigned)j);  // val desc, idx asc
  }
  __syncthreads();
  for (int round = 0; round < TOPK; ++round) {
    unsigned long long best = 0ULL; int bslot = 0;
    for (int j = tid; j < N; j += 256)
      if (keys[j] > best) { best = keys[j]; bslot = j; }
    rbest[tid] = best; rslot[tid] = bslot;
    __syncthreads();
    for (int off = 128; off > 0; off >>= 1) {
      if (tid < off && rbest[tid + off] > rbest[tid]) {
        rbest[tid] = rbest[tid + off]; rslot[tid] = rslot[tid + off];
      }
      __syncthreads();
    }
    if (tid == 0) {
      topk[i * TOPK + round] = (int)(0xFFFFFFFFu - (unsigned)(rbest[0] & 0xFFFFFFFFu));
      keys[rslot[0]] = 0ULL;
    }
    __syncthreads();
  }
}

// ---------------- K4: mutual-kNN lists L_i, cnt_i ----------------
__global__ void k_buildV(const int* __restrict__ topk, int* __restrict__ L,
                         int* __restrict__ cnt) {
  int i = blockIdx.x * 256 + threadIdx.x;
  if (i >= N) return;
  int c = 0;
  for (int r = 0; r < TOPK; ++r) {
    int j = topk[i * TOPK + r];
    bool mut = false;
    for (int q = 0; q < TOPK; ++q) mut |= (topk[j * TOPK + q] == i);
    if (mut) L[i * TOPK + c++] = j;
  }
  cnt[i] = c;
}

// ---------------- K5: sparse W_C loss term ----------------
// T3 = (1/20) * sum_i sum_{m<5} sum_{j in L_r, j!=i} (VV[r][j]/max(cnt_r,1)) * (F_ij + F_ji)
__global__ void k_wc(const int* __restrict__ topk, const int* __restrict__ L,
                     const int* __restrict__ cnt, const float* __restrict__ Gs,
                     const float* __restrict__ rsq, const float* __restrict__ mean,
                     double* acc) {
  int t = blockIdx.x * 256 + threadIdx.x;
  if (t >= N * TOPK_HALF) return;
  int i = t / TOPK_HALF, m = t % TOPK_HALF;
  int r = topk[i * TOPK + m];
  int cr = cnt[r];
  if (cr == 0) return;
  float denom = (float)(cr > 1 ? cr : 1);
  int Lr[TOPK];
  for (int a = 0; a < cr; ++a) Lr[a] = L[r * TOPK + a];
  float rsi = rsq[i];
  float invmi = 1.0f / mean[i];
  double local = 0.0;
  for (int jj = 0; jj < cr; ++jj) {
    int j = Lr[jj];
    if (j == i) continue;
    int cj = cnt[j];
    int vv = 0;
    for (int a = 0; a < cr; ++a) {
      int la = Lr[a];
      for (int b = 0; b < cj; ++b) vv += (la == L[j * TOPK + b]) ? 1 : 0;
    }
    float w = (float)vv / denom;
    float g = Gs[(size_t)i * N + j];
    float sq = fmaxf(rsi + rsq[j] - 2.0f * g, 0.0f);
    float sr = sqrtf(sq);
    float sdij = sr * invmi;
    float sdji = sr / mean[j];
    float Rij = fmaxf(1.0f - sdij, 0.0f); Rij *= Rij;
    float Rji = fmaxf(1.0f - sdji, 0.0f); Rji *= Rji;
    float Fij = sdij * sdij - Rij;
    float Fji = sdji * sdji - Rji;
    local += (double)(w * (Fij + Fji));
  }
  if (local != 0.0) atomicAdd(acc, local * (1.0 / 20.0));
}

// ---------------- K6: dense loss  sum_{i!=j} R + 0.5*W_P*(Sd^2 - R) ----------------
__global__ __launch_bounds__(256) void k_dense(const float* __restrict__ Gs,
                                               const float* __restrict__ Gt,
                                               const float* __restrict__ rsq_s,
                                               const float* __restrict__ rsq_t,
                                               const float* __restrict__ mean,
                                               double* acc) {
  int i = blockIdx.y;
  int tid = threadIdx.x;
  int j0 = blockIdx.x * 1024 + tid * 4;
  float rsi = rsq_s[i], rti = rsq_t[i];
  float invm = 1.0f / mean[i];
  float4 gs4 = *(const float4*)(Gs + (size_t)i * N + j0);
  float4 gt4 = *(const float4*)(Gt + (size_t)i * N + j0);
  float sum = 0.f;
  const float* gs = (const float*)&gs4;
  const float* gt = (const float*)&gt4;
#pragma unroll
  for (int u = 0; u < 4; ++u) {
    int j = j0 + u;
    if (j == i) continue;
    float ssq = fmaxf(rsi + rsq_s[j] - 2.0f * gs[u], 0.0f);
    float sd = sqrtf(ssq) * invm;
    float r = fmaxf(1.0f - sd, 0.0f); r *= r;
    float tsq = fmaxf(rti + rsq_t[j] - 2.0f * gt[u], 0.0f);
    float wp = expf(-tsq);
    sum += r + 0.5f * wp * (sd * sd - r);
  }
  __shared__ float red[4];
  for (int off = 32; off > 0; off >>= 1) sum += __shfl_down(sum, off, 64);
  if ((tid & 63) == 0) red[tid >> 6] = sum;
  __syncthreads();
  if (tid == 0) atomicAdd(acc, (double)(red[0] + red[1] + red[2] + red[3]));
}

// ---------------- K7: finalize ----------------
__global__ void k_final(const double* acc, float* out) {
  out[0] = (float)(acc[0] / ((double)N * (double)(N - 1)));
}

extern "C" void kernel_launch(void* const* d_in, const int* in_sizes, int n_in,
                              void* d_out, int out_size, void* d_ws, size_t ws_size,
                              hipStream_t stream) {
  const float* s_emb = (const float*)d_in[0];
  const float* t_emb = (const float*)d_in[1];
  const int* ids = (const int*)d_in[2];
  float* out = (float*)d_out;

  char* ws = (char*)d_ws;
  size_t off = 0;
  float* snorm = (float*)(ws + off); off += (size_t)N * D * 4;      // 8 MB
  float* tnorm = (float*)(ws + off); off += (size_t)N * D * 4;      // 8 MB
  float* Gs    = (float*)(ws + off); off += (size_t)N * N * 4;      // 64 MB
  float* Gt    = (float*)(ws + off); off += (size_t)N * N * 4;      // 64 MB
  float* rsq_s = (float*)(ws + off); off += (size_t)N * 4;
  float* rsq_t = (float*)(ws + off); off += (size_t)N * 4;
  float* mean  = (float*)(ws + off); off += (size_t)N * 4;
  int*   topk  = (int*)(ws + off);   off += (size_t)N * TOPK * 4;
  int*   L     = (int*)(ws + off);   off += (size_t)N * TOPK * 4;
  int*   cnt   = (int*)(ws + off);   off += (size_t)N * 4;
  off = (off + 15) & ~(size_t)15;
  double* acc  = (double*)(ws + off); off += 16;

  k_init<<<1, 1, 0, stream>>>(acc);
  k_normalize<<<N, 256, 0, stream>>>(s_emb, snorm, rsq_s);
  k_normalize<<<N, 256, 0, stream>>>(t_emb, tnorm, rsq_t);
  dim3 gg(N / BN, N / BM);
  k_gram<<<gg, 256, 0, stream>>>(snorm, Gs);
  k_gram<<<gg, 256, 0, stream>>>(tnorm, Gt);
  k_rowmean<<<N, 256, 0, stream>>>(Gs, rsq_s, mean);
  k_topk<<<N, 256, 0, stream>>>(Gt, rsq_t, ids, topk);
  k_buildV<<<N / 256, 256, 0, stream>>>(topk, L, cnt);
  k_wc<<<(N * TOPK_HALF + 255) / 256, 256, 0, stream>>>(topk, L, cnt, Gs, rsq_s, mean, acc);
  k_dense<<<dim3(N / 1024, N), 256, 0, stream>>>(Gs, Gt, rsq_s, rsq_t, mean, acc);
  k_final<<<1, 1, 0, stream>>>(acc, out);
}

// Round 2
// 500.825 us; speedup vs baseline: 1.9058x; 1.9058x over previous
//
#include <hip/hip_runtime.h>
#include <math.h>

#define N 4096
#define D 512
#define TOPK 10
#define TOPK_HALF 5

typedef __bf16 bf16;
typedef __bf16 bf16x8 __attribute__((ext_vector_type(8)));
typedef float f32x4 __attribute__((ext_vector_type(4)));
typedef unsigned long long u64;

__device__ __forceinline__ void gl_lds16(const void* g, void* l) {
  __builtin_amdgcn_global_load_lds(
      (const __attribute__((address_space(1))) void*)g,
      (__attribute__((address_space(3))) void*)l, 16, 0, 0);
}

// ---------------- zero rowsum + acc ----------------
__global__ void k_zero(float* rowsum, double* acc) {
  int i = blockIdx.x * 256 + threadIdx.x;
  if (i < N) rowsum[i] = 0.f;
  if (i == 0) acc[0] = 0.0;
}

// ---------------- K0: L2-normalize -> bf16 rows + rsq of bf16 values ----------------
__global__ __launch_bounds__(256) void k_normalize(const float* __restrict__ x,
                                                   bf16* __restrict__ y,
                                                   float* __restrict__ rowsq) {
  int row = blockIdx.x, tid = threadIdx.x;
  const float* xr = x + (size_t)row * D;
  float v0 = xr[tid], v1 = xr[tid + 256];
  float ss = v0 * v0 + v1 * v1;
  __shared__ float red[4];
  for (int off = 32; off > 0; off >>= 1) ss += __shfl_down(ss, off, 64);
  if ((tid & 63) == 0) red[tid >> 6] = ss;
  __syncthreads();
  float tot = red[0] + red[1] + red[2] + red[3];
  float inv = 1.0f / fmaxf(sqrtf(tot), 1e-12f);
  bf16 b0 = (bf16)(v0 * inv), b1 = (bf16)(v1 * inv);
  bf16* yr = y + (size_t)row * D;
  yr[tid] = b0; yr[tid + 256] = b1;
  float f0 = (float)b0, f1 = (float)b1;
  float s2 = f0 * f0 + f1 * f1;
  for (int off = 32; off > 0; off >>= 1) s2 += __shfl_down(s2, off, 64);
  __syncthreads();
  if ((tid & 63) == 0) red[tid >> 6] = s2;
  __syncthreads();
  if (tid == 0) rowsq[row] = red[0] + red[1] + red[2] + red[3];
}

// ---------------- K1: MFMA bf16 Gram, fused epilogue ----------------
// MODE 0: G = sqrt(max(rsq_i+rsq_j-2*dot,0))  (raw S_dist) + rowsum atomics
// MODE 1: G = exp(-max(sq,0))                 (W_P)
template <int MODE>
__global__ __launch_bounds__(256) void k_gram(const bf16* __restrict__ Y,
                                              const float* __restrict__ rsq,
                                              float* __restrict__ G,
                                              float* __restrict__ rowsum) {
  __shared__ bf16 As[128 * 32];
  __shared__ bf16 Bs[128 * 32];
  int bx = blockIdx.x, by = blockIdx.y;
  int tid = threadIdx.x;
  int lane = tid & 63, w = tid >> 6;
  int wr = w >> 1, wc = w & 1;
  f32x4 acc[4][4] = {};

  const char* Abase = (const char*)(Y + (size_t)(by * 128) * D);
  const char* Bbase = (const char*)(Y + (size_t)(bx * 128) * D);
  // chunk c (0..511) covers As[c>>2][ (c&3)*8 .. +8 ]  (16 B)
  int c0 = tid, c1 = tid + 256;
  int r0 = c0 >> 2, q0 = c0 & 3;
  int r1 = c1 >> 2, q1 = c1 & 3;
  // wave-uniform LDS bases (HW writes base + lane*16)
  bf16* lA0 = As + (size_t)(w * 64) * 8;
  bf16* lA1 = As + (size_t)(256 + w * 64) * 8;
  bf16* lB0 = Bs + (size_t)(w * 64) * 8;
  bf16* lB1 = Bs + (size_t)(256 + w * 64) * 8;

  int arow = wr * 64 + (lane & 15);
  int brow = wc * 64 + (lane & 15);
  int kq = (lane >> 4) * 8;

  for (int k0 = 0; k0 < D; k0 += 32) {
    size_t off0 = (size_t)r0 * (D * 2) + (size_t)k0 * 2 + q0 * 16;
    size_t off1 = (size_t)r1 * (D * 2) + (size_t)k0 * 2 + q1 * 16;
    gl_lds16(Abase + off0, lA0);
    gl_lds16(Abase + off1, lA1);
    gl_lds16(Bbase + off0, lB0);
    gl_lds16(Bbase + off1, lB1);
    __syncthreads();
    bf16x8 af[4], bfr[4];
#pragma unroll
    for (int u = 0; u < 4; ++u) af[u] = *(bf16x8*)&As[(arow + u * 16) * 32 + kq];
#pragma unroll
    for (int v = 0; v < 4; ++v) bfr[v] = *(bf16x8*)&Bs[(brow + v * 16) * 32 + kq];
#pragma unroll
    for (int u = 0; u < 4; ++u)
#pragma unroll
      for (int v = 0; v < 4; ++v)
        acc[u][v] = __builtin_amdgcn_mfma_f32_16x16x32_bf16(af[u], bfr[v], acc[u][v], 0, 0, 0);
    __syncthreads();
  }

  // epilogue: C row = (lane>>4)*4+reg, col = lane&15 within each 16x16 tile
  int colb = bx * 128 + wc * 64 + (lane & 15);
  int rowb = by * 128 + wr * 64 + ((lane >> 4) << 2);
  float rsc[4];
#pragma unroll
  for (int v = 0; v < 4; ++v) rsc[v] = rsq[colb + v * 16];
#pragma unroll
  for (int u = 0; u < 4; ++u) {
    float rsr[4];
#pragma unroll
    for (int reg = 0; reg < 4; ++reg) rsr[reg] = rsq[rowb + u * 16 + reg];
    float rpart[4] = {0.f, 0.f, 0.f, 0.f};
#pragma unroll
    for (int v = 0; v < 4; ++v) {
      f32x4 a = acc[u][v];
#pragma unroll
      for (int reg = 0; reg < 4; ++reg) {
        float sq = fmaxf(rsr[reg] + rsc[v] - 2.0f * a[reg], 0.0f);
        float val = (MODE == 0) ? sqrtf(sq) : expf(-sq);
        G[(size_t)(rowb + u * 16 + reg) * N + colb + v * 16] = val;
        if (MODE == 0) rpart[reg] += val;
      }
    }
    if (MODE == 0) {
#pragma unroll
      for (int reg = 0; reg < 4; ++reg) {
        float s = rpart[reg];
        s += __shfl_xor(s, 1, 64);
        s += __shfl_xor(s, 2, 64);
        s += __shfl_xor(s, 4, 64);
        s += __shfl_xor(s, 8, 64);
        if ((lane & 15) == 0) atomicAdd(&rowsum[rowb + u * 16 + reg], s);
      }
    }
  }
}

// ---------------- K2: mean = rowsum / N ----------------
__global__ void k_mean(const float* __restrict__ rowsum, float* __restrict__ mean) {
  int i = blockIdx.x * 256 + threadIdx.x;
  if (i < N) mean[i] = rowsum[i] * (1.0f / (float)N);
}

// ---------------- K3: exact top-10 per row (register insertion + LDS merge) ----------------
__global__ __launch_bounds__(256) void k_topk(const float* __restrict__ Wp,
                                              const int* __restrict__ ids,
                                              int* __restrict__ topk) {
  __shared__ u64 lds[256 * TOPK];  // 20 KB
  int i = blockIdx.x, tid = threadIdx.x;
  int idi = ids[i];
  const float* row = Wp + (size_t)i * N;
  u64 top[TOPK];
#pragma unroll
  for (int o = 0; o < TOPK; ++o) top[o] = 0ULL;
#pragma unroll
  for (int s = 0; s < 4; ++s) {
    int j0 = s * 1024 + tid * 4;
    float4 w4 = *(const float4*)(row + j0);
    const float* wv = (const float*)&w4;
#pragma unroll
    for (int u = 0; u < 4; ++u) {
      int j = j0 + u;
      float w = (ids[j] == idi) ? 1.0f : wv[u];
      u64 key = ((u64)__float_as_uint(w) << 32) |
                (u64)(0xFFFFFFFFu - (unsigned)j);  // val desc, idx asc
      if (key > top[TOPK - 1]) {
        top[TOPK - 1] = key;
#pragma unroll
        for (int a = TOPK - 2; a >= 0; --a) {
          if (top[a + 1] > top[a]) { u64 t = top[a]; top[a] = top[a + 1]; top[a + 1] = t; }
        }
      }
    }
  }
#pragma unroll
  for (int o = 0; o < TOPK; ++o) lds[tid * TOPK + o] = top[o];
  __syncthreads();
  for (int off = 128; off >= 1; off >>= 1) {
    if (tid < off) {
      u64 out[TOPK];
      int pa = 0, pb = 0;
#pragma unroll
      for (int o = 0; o < TOPK; ++o) {
        u64 ka = (pa < TOPK) ? lds[tid * TOPK + pa] : 0ULL;
        u64 kb = (pb < TOPK) ? lds[(tid + off) * TOPK + pb] : 0ULL;
        bool ta = ka >= kb;
        out[o] = ta ? ka : kb;
        pa += ta ? 1 : 0;
        pb += ta ? 0 : 1;
      }
#pragma unroll
      for (int o = 0; o < TOPK; ++o) lds[tid * TOPK + o] = out[o];
    }
    __syncthreads();
  }
  if (tid == 0) {
#pragma unroll
    for (int o = 0; o < TOPK; ++o)
      topk[i * TOPK + o] = (int)(0xFFFFFFFFu - (unsigned)(lds[o] & 0xFFFFFFFFu));
  }
}

// ---------------- K4: mutual-kNN lists ----------------
__global__ void k_buildV(const int* __restrict__ topk, int* __restrict__ L,
                         int* __restrict__ cnt) {
  int i = blockIdx.x * 256 + threadIdx.x;
  if (i >= N) return;
  int c = 0;
  for (int r = 0; r < TOPK; ++r) {
    int j = topk[i * TOPK + r];
    bool mut = false;
    for (int q = 0; q < TOPK; ++q) mut |= (topk[j * TOPK + q] == i);
    if (mut) L[i * TOPK + c++] = j;
  }
  cnt[i] = c;
}

// ---------------- K5: sparse W_C loss term ----------------
__global__ void k_wc(const int* __restrict__ topk, const int* __restrict__ L,
                     const int* __restrict__ cnt, const float* __restrict__ Gs,
                     const float* __restrict__ mean, double* acc) {
  int t = blockIdx.x * 256 + threadIdx.x;
  if (t >= N * TOPK_HALF) return;
  int i = t / TOPK_HALF, m = t % TOPK_HALF;
  int r = topk[i * TOPK + m];
  int cr = cnt[r];
  if (cr == 0) return;
  float denom = (float)(cr > 1 ? cr : 1);
  int Lr[TOPK];
  for (int a = 0; a < cr; ++a) Lr[a] = L[r * TOPK + a];
  float invmi = 1.0f / mean[i];
  double local = 0.0;
  for (int jj = 0; jj < cr; ++jj) {
    int j = Lr[jj];
    if (j == i) continue;
    int cj = cnt[j];
    int vv = 0;
    for (int a = 0; a < cr; ++a) {
      int la = Lr[a];
      for (int b = 0; b < cj; ++b) vv += (la == L[j * TOPK + b]) ? 1 : 0;
    }
    float wgt = (float)vv / denom;
    float sr = Gs[(size_t)i * N + j];
    float sdij = sr * invmi;
    float sdji = sr / mean[j];
    float Rij = fmaxf(1.0f - sdij, 0.0f); Rij *= Rij;
    float Rji = fmaxf(1.0f - sdji, 0.0f); Rji *= Rji;
    float Fij = sdij * sdij - Rij;
    float Fji = sdji * sdji - Rji;
    local += (double)(wgt * (Fij + Fji));
  }
  if (local != 0.0) atomicAdd(acc, local * (1.0 / 20.0));
}

// ---------------- K6: dense loss ----------------
__global__ __launch_bounds__(256) void k_dense(const float* __restrict__ Gs,
                                               const float* __restrict__ Gt,
                                               const float* __restrict__ mean,
                                               double* acc) {
  int i = blockIdx.y;
  int tid = threadIdx.x;
  int j0 = blockIdx.x * 1024 + tid * 4;
  float invm = 1.0f / mean[i];
  float4 gs4 = *(const float4*)(Gs + (size_t)i * N + j0);
  float4 gt4 = *(const float4*)(Gt + (size_t)i * N + j0);
  float sum = 0.f;
  const float* gs = (const float*)&gs4;
  const float* gt = (const float*)&gt4;
#pragma unroll
  for (int u = 0; u < 4; ++u) {
    int j = j0 + u;
    if (j == i) continue;
    float sd = gs[u] * invm;
    float r = fmaxf(1.0f - sd, 0.0f); r *= r;
    float wp = gt[u];
    sum += r + 0.5f * wp * (sd * sd - r);
  }
  __shared__ float red[4];
  for (int off = 32; off > 0; off >>= 1) sum += __shfl_down(sum, off, 64);
  if ((tid & 63) == 0) red[tid >> 6] = sum;
  __syncthreads();
  if (tid == 0) atomicAdd(acc, (double)(red[0] + red[1] + red[2] + red[3]));
}

// ---------------- K7: finalize ----------------
__global__ void k_final(const double* acc, float* out) {
  out[0] = (float)(acc[0] / ((double)N * (double)(N - 1)));
}

extern "C" void kernel_launch(void* const* d_in, const int* in_sizes, int n_in,
                              void* d_out, int out_size, void* d_ws, size_t ws_size,
                              hipStream_t stream) {
  const float* s_emb = (const float*)d_in[0];
  const float* t_emb = (const float*)d_in[1];
  const int* ids = (const int*)d_in[2];
  float* out = (float*)d_out;

  char* ws = (char*)d_ws;
  size_t off = 0;
  bf16* snorm = (bf16*)(ws + off); off += (size_t)N * D * 2;        // 4 MB
  bf16* tnorm = (bf16*)(ws + off); off += (size_t)N * D * 2;        // 4 MB
  float* Gs    = (float*)(ws + off); off += (size_t)N * N * 4;      // 64 MB
  float* Gt    = (float*)(ws + off); off += (size_t)N * N * 4;      // 64 MB
  float* rsq_s = (float*)(ws + off); off += (size_t)N * 4;
  float* rsq_t = (float*)(ws + off); off += (size_t)N * 4;
  float* rowsum= (float*)(ws + off); off += (size_t)N * 4;
  float* mean  = (float*)(ws + off); off += (size_t)N * 4;
  int*   topk  = (int*)(ws + off);   off += (size_t)N * TOPK * 4;
  int*   L     = (int*)(ws + off);   off += (size_t)N * TOPK * 4;
  int*   cnt   = (int*)(ws + off);   off += (size_t)N * 4;
  off = (off + 15) & ~(size_t)15;
  double* acc  = (double*)(ws + off); off += 16;

  k_zero<<<16, 256, 0, stream>>>(rowsum, acc);
  k_normalize<<<N, 256, 0, stream>>>(s_emb, snorm, rsq_s);
  k_normalize<<<N, 256, 0, stream>>>(t_emb, tnorm, rsq_t);
  dim3 gg(N / 128, N / 128);
  k_gram<0><<<gg, 256, 0, stream>>>(snorm, rsq_s, Gs, rowsum);
  k_gram<1><<<gg, 256, 0, stream>>>(tnorm, rsq_t, Gt, nullptr);
  k_mean<<<16, 256, 0, stream>>>(rowsum, mean);
  k_topk<<<N, 256, 0, stream>>>(Gt, ids, topk);
  k_buildV<<<N / 256, 256, 0, stream>>>(topk, L, cnt);
  k_wc<<<(N * TOPK_HALF + 255) / 256, 256, 0, stream>>>(topk, L, cnt, Gs, mean, acc);
  k_dense<<<dim3(N / 1024, N), 256, 0, stream>>>(Gs, Gt, mean, acc);
  k_final<<<1, 1, 0, stream>>>(acc, out);
}

// Round 3
// 294.014 us; speedup vs baseline: 3.2463x; 1.7034x over previous
//
#include <hip/hip_runtime.h>
#include <math.h>

#define N 4096
#define D 512
#define TOPK 10
#define TOPK_HALF 5
#define NWC_BLOCKS ((N * TOPK_HALF + 255) / 256)

typedef __bf16 bf16;
typedef __bf16 bf16x8 __attribute__((ext_vector_type(8)));
typedef float f32x4 __attribute__((ext_vector_type(4)));
typedef unsigned long long u64;

__device__ __forceinline__ void gl_lds16(const void* g, void* l) {
  __builtin_amdgcn_global_load_lds(
      (const __attribute__((address_space(1))) void*)g,
      (__attribute__((address_space(3))) void*)l, 16, 0, 0);
}

// ---------------- zero rowsum ----------------
__global__ void k_zero(float* rowsum) {
  int i = blockIdx.x * 256 + threadIdx.x;
  if (i < N) rowsum[i] = 0.f;
}

// ---------------- K0: L2-normalize -> bf16 rows + rsq of bf16 values ----------------
__global__ __launch_bounds__(256) void k_normalize(const float* __restrict__ x,
                                                   bf16* __restrict__ y,
                                                   float* __restrict__ rowsq) {
  int row = blockIdx.x, tid = threadIdx.x;
  const float* xr = x + (size_t)row * D;
  float v0 = xr[tid], v1 = xr[tid + 256];
  float ss = v0 * v0 + v1 * v1;
  __shared__ float red[4];
  for (int off = 32; off > 0; off >>= 1) ss += __shfl_down(ss, off, 64);
  if ((tid & 63) == 0) red[tid >> 6] = ss;
  __syncthreads();
  float tot = red[0] + red[1] + red[2] + red[3];
  float inv = 1.0f / fmaxf(sqrtf(tot), 1e-12f);
  bf16 b0 = (bf16)(v0 * inv), b1 = (bf16)(v1 * inv);
  bf16* yr = y + (size_t)row * D;
  yr[tid] = b0; yr[tid + 256] = b1;
  float f0 = (float)b0, f1 = (float)b1;
  float s2 = f0 * f0 + f1 * f1;
  for (int off = 32; off > 0; off >>= 1) s2 += __shfl_down(s2, off, 64);
  __syncthreads();
  if ((tid & 63) == 0) red[tid >> 6] = s2;
  __syncthreads();
  if (tid == 0) rowsq[row] = red[0] + red[1] + red[2] + red[3];
}

// ---------------- K1: MFMA bf16 Gram, fused epilogue ----------------
// MODE 0: G = sqrt(max(rsq_i+rsq_j-2*dot,0))  (raw S_dist) + rowsum atomics
// MODE 1: G = exp(-max(sq,0))                 (W_P)
template <int MODE>
__global__ __launch_bounds__(256) void k_gram(const bf16* __restrict__ Y,
                                              const float* __restrict__ rsq,
                                              float* __restrict__ G,
                                              float* __restrict__ rowsum) {
  __shared__ bf16 As[128 * 32];
  __shared__ bf16 Bs[128 * 32];
  int bx = blockIdx.x, by = blockIdx.y;
  int tid = threadIdx.x;
  int lane = tid & 63, w = tid >> 6;
  int wr = w >> 1, wc = w & 1;
  f32x4 acc[4][4] = {};

  const char* Abase = (const char*)(Y + (size_t)(by * 128) * D);
  const char* Bbase = (const char*)(Y + (size_t)(bx * 128) * D);
  int c0 = tid, c1 = tid + 256;
  int r0 = c0 >> 2, q0 = c0 & 3;
  int r1 = c1 >> 2, q1 = c1 & 3;
  bf16* lA0 = As + (size_t)(w * 64) * 8;
  bf16* lA1 = As + (size_t)(256 + w * 64) * 8;
  bf16* lB0 = Bs + (size_t)(w * 64) * 8;
  bf16* lB1 = Bs + (size_t)(256 + w * 64) * 8;

  int arow = wr * 64 + (lane & 15);
  int brow = wc * 64 + (lane & 15);
  int kq = (lane >> 4) * 8;

  for (int k0 = 0; k0 < D; k0 += 32) {
    size_t off0 = (size_t)r0 * (D * 2) + (size_t)k0 * 2 + q0 * 16;
    size_t off1 = (size_t)r1 * (D * 2) + (size_t)k0 * 2 + q1 * 16;
    gl_lds16(Abase + off0, lA0);
    gl_lds16(Abase + off1, lA1);
    gl_lds16(Bbase + off0, lB0);
    gl_lds16(Bbase + off1, lB1);
    __syncthreads();
    bf16x8 af[4], bfr[4];
#pragma unroll
    for (int u = 0; u < 4; ++u) af[u] = *(bf16x8*)&As[(arow + u * 16) * 32 + kq];
#pragma unroll
    for (int v = 0; v < 4; ++v) bfr[v] = *(bf16x8*)&Bs[(brow + v * 16) * 32 + kq];
#pragma unroll
    for (int u = 0; u < 4; ++u)
#pragma unroll
      for (int v = 0; v < 4; ++v)
        acc[u][v] = __builtin_amdgcn_mfma_f32_16x16x32_bf16(af[u], bfr[v], acc[u][v], 0, 0, 0);
    __syncthreads();
  }

  int colb = bx * 128 + wc * 64 + (lane & 15);
  int rowb = by * 128 + wr * 64 + ((lane >> 4) << 2);
  float rsc[4];
#pragma unroll
  for (int v = 0; v < 4; ++v) rsc[v] = rsq[colb + v * 16];
#pragma unroll
  for (int u = 0; u < 4; ++u) {
    float rsr[4];
#pragma unroll
    for (int reg = 0; reg < 4; ++reg) rsr[reg] = rsq[rowb + u * 16 + reg];
    float rpart[4] = {0.f, 0.f, 0.f, 0.f};
#pragma unroll
    for (int v = 0; v < 4; ++v) {
      f32x4 a = acc[u][v];
#pragma unroll
      for (int reg = 0; reg < 4; ++reg) {
        float sq = fmaxf(rsr[reg] + rsc[v] - 2.0f * a[reg], 0.0f);
        float val = (MODE == 0) ? sqrtf(sq) : expf(-sq);
        G[(size_t)(rowb + u * 16 + reg) * N + colb + v * 16] = val;
        if (MODE == 0) rpart[reg] += val;
      }
    }
    if (MODE == 0) {
#pragma unroll
      for (int reg = 0; reg < 4; ++reg) {
        float s = rpart[reg];
        s += __shfl_xor(s, 1, 64);
        s += __shfl_xor(s, 2, 64);
        s += __shfl_xor(s, 4, 64);
        s += __shfl_xor(s, 8, 64);
        if ((lane & 15) == 0) atomicAdd(&rowsum[rowb + u * 16 + reg], s);
      }
    }
  }
}

// ---------------- K2: mean = rowsum / N ----------------
__global__ void k_mean(const float* __restrict__ rowsum, float* __restrict__ mean) {
  int i = blockIdx.x * 256 + threadIdx.x;
  if (i < N) mean[i] = rowsum[i] * (1.0f / (float)N);
}

// ---------------- K3: fused row pass: exact top-10 + dense loss partial ----------------
// One block per row i. Streams Gs row + Gt(Wp) row once.
__global__ __launch_bounds__(256) void k_rowpass(const float* __restrict__ Gs,
                                                 const float* __restrict__ Wp,
                                                 const int* __restrict__ ids,
                                                 const float* __restrict__ mean,
                                                 int* __restrict__ topk,
                                                 double* __restrict__ pd) {
  __shared__ u64 lds[256 * TOPK];  // 20 KB
  __shared__ double dred[4];
  int i = blockIdx.x, tid = threadIdx.x;
  int idi = ids[i];
  float invm = 1.0f / mean[i];
  const float* wrow = Wp + (size_t)i * N;
  const float* srow = Gs + (size_t)i * N;
  u64 top[TOPK];
#pragma unroll
  for (int o = 0; o < TOPK; ++o) top[o] = 0ULL;
  float dsum = 0.f;
#pragma unroll
  for (int s = 0; s < 4; ++s) {
    int j0 = s * 1024 + tid * 4;
    float4 w4 = *(const float4*)(wrow + j0);
    float4 g4 = *(const float4*)(srow + j0);
    const float* wv = (const float*)&w4;
    const float* gv = (const float*)&g4;
#pragma unroll
    for (int u = 0; u < 4; ++u) {
      int j = j0 + u;
      float wkey = (ids[j] == idi) ? 1.0f : wv[u];
      u64 key = ((u64)__float_as_uint(wkey) << 32) |
                (u64)(0xFFFFFFFFu - (unsigned)j);  // val desc, idx asc
      if (key > top[TOPK - 1]) {
        top[TOPK - 1] = key;
#pragma unroll
        for (int a = TOPK - 2; a >= 0; --a) {
          if (top[a + 1] > top[a]) { u64 t = top[a]; top[a] = top[a + 1]; top[a + 1] = t; }
        }
      }
      if (j != i) {
        float sd = gv[u] * invm;
        float r = fmaxf(1.0f - sd, 0.0f); r *= r;
        dsum += r + 0.5f * wv[u] * (sd * sd - r);
      }
    }
  }
  // dense-loss block reduction (double)
  double dl = (double)dsum;
  for (int off = 32; off > 0; off >>= 1) dl += __shfl_down(dl, off, 64);
  if ((tid & 63) == 0) dred[tid >> 6] = dl;
  // top-k merge tree
#pragma unroll
  for (int o = 0; o < TOPK; ++o) lds[tid * TOPK + o] = top[o];
  __syncthreads();
  for (int off = 128; off >= 1; off >>= 1) {
    if (tid < off) {
      u64 out[TOPK];
      int pa = 0, pb = 0;
#pragma unroll
      for (int o = 0; o < TOPK; ++o) {
        u64 ka = (pa < TOPK) ? lds[tid * TOPK + pa] : 0ULL;
        u64 kb = (pb < TOPK) ? lds[(tid + off) * TOPK + pb] : 0ULL;
        bool ta = ka >= kb;
        out[o] = ta ? ka : kb;
        pa += ta ? 1 : 0;
        pb += ta ? 0 : 1;
      }
#pragma unroll
      for (int o = 0; o < TOPK; ++o) lds[tid * TOPK + o] = out[o];
    }
    __syncthreads();
  }
  if (tid == 0) {
#pragma unroll
    for (int o = 0; o < TOPK; ++o)
      topk[i * TOPK + o] = (int)(0xFFFFFFFFu - (unsigned)(lds[o] & 0xFFFFFFFFu));
    pd[i] = dred[0] + dred[1] + dred[2] + dred[3];
  }
}

// ---------------- K4: mutual-kNN lists ----------------
__global__ void k_buildV(const int* __restrict__ topk, int* __restrict__ L,
                         int* __restrict__ cnt) {
  int i = blockIdx.x * 256 + threadIdx.x;
  if (i >= N) return;
  int c = 0;
  for (int r = 0; r < TOPK; ++r) {
    int j = topk[i * TOPK + r];
    bool mut = false;
    for (int q = 0; q < TOPK; ++q) mut |= (topk[j * TOPK + q] == i);
    if (mut) L[i * TOPK + c++] = j;
  }
  cnt[i] = c;
}

// ---------------- K5: sparse W_C loss term, per-block partials ----------------
__global__ __launch_bounds__(256) void k_wc(const int* __restrict__ topk,
                                            const int* __restrict__ L,
                                            const int* __restrict__ cnt,
                                            const float* __restrict__ Gs,
                                            const float* __restrict__ mean,
                                            double* __restrict__ pw) {
  int tid = threadIdx.x;
  int t = blockIdx.x * 256 + tid;
  double local = 0.0;
  if (t < N * TOPK_HALF) {
    int i = t / TOPK_HALF, m = t % TOPK_HALF;
    int r = topk[i * TOPK + m];
    int cr = cnt[r];
    if (cr > 0) {
      float denom = (float)(cr > 1 ? cr : 1);
      int Lr[TOPK];
      for (int a = 0; a < cr; ++a) Lr[a] = L[r * TOPK + a];
      float invmi = 1.0f / mean[i];
      for (int jj = 0; jj < cr; ++jj) {
        int j = Lr[jj];
        if (j == i) continue;
        int cj = cnt[j];
        int vv = 0;
        for (int a = 0; a < cr; ++a) {
          int la = Lr[a];
          for (int b = 0; b < cj; ++b) vv += (la == L[j * TOPK + b]) ? 1 : 0;
        }
        float wgt = (float)vv / denom;
        float sr = Gs[(size_t)i * N + j];
        float sdij = sr * invmi;
        float sdji = sr / mean[j];
        float Rij = fmaxf(1.0f - sdij, 0.0f); Rij *= Rij;
        float Rji = fmaxf(1.0f - sdji, 0.0f); Rji *= Rji;
        float Fij = sdij * sdij - Rij;
        float Fji = sdji * sdji - Rji;
        local += (double)(wgt * (Fij + Fji));
      }
      local *= (1.0 / 20.0);
    }
  }
  __shared__ double red[4];
  for (int off = 32; off > 0; off >>= 1) local += __shfl_down(local, off, 64);
  if ((tid & 63) == 0) red[tid >> 6] = local;
  __syncthreads();
  if (tid == 0) pw[blockIdx.x] = red[0] + red[1] + red[2] + red[3];
}

// ---------------- K6: final reduce ----------------
__global__ __launch_bounds__(256) void k_final(const double* __restrict__ pd,
                                               const double* __restrict__ pw,
                                               float* __restrict__ out) {
  int tid = threadIdx.x;
  double s = 0.0;
  for (int i = tid; i < N; i += 256) s += pd[i];
  for (int i = tid; i < NWC_BLOCKS; i += 256) s += pw[i];
  for (int off = 32; off > 0; off >>= 1) s += __shfl_down(s, off, 64);
  __shared__ double red[4];
  if ((tid & 63) == 0) red[tid >> 6] = s;
  __syncthreads();
  if (tid == 0)
    out[0] = (float)((red[0] + red[1] + red[2] + red[3]) /
                     ((double)N * (double)(N - 1)));
}

extern "C" void kernel_launch(void* const* d_in, const int* in_sizes, int n_in,
                              void* d_out, int out_size, void* d_ws, size_t ws_size,
                              hipStream_t stream) {
  const float* s_emb = (const float*)d_in[0];
  const float* t_emb = (const float*)d_in[1];
  const int* ids = (const int*)d_in[2];
  float* out = (float*)d_out;

  char* ws = (char*)d_ws;
  size_t off = 0;
  bf16* snorm = (bf16*)(ws + off); off += (size_t)N * D * 2;        // 4 MB
  bf16* tnorm = (bf16*)(ws + off); off += (size_t)N * D * 2;        // 4 MB
  float* Gs    = (float*)(ws + off); off += (size_t)N * N * 4;      // 64 MB
  float* Gt    = (float*)(ws + off); off += (size_t)N * N * 4;      // 64 MB
  float* rsq_s = (float*)(ws + off); off += (size_t)N * 4;
  float* rsq_t = (float*)(ws + off); off += (size_t)N * 4;
  float* rowsum= (float*)(ws + off); off += (size_t)N * 4;
  float* mean  = (float*)(ws + off); off += (size_t)N * 4;
  int*   topk  = (int*)(ws + off);   off += (size_t)N * TOPK * 4;
  int*   L     = (int*)(ws + off);   off += (size_t)N * TOPK * 4;
  int*   cnt   = (int*)(ws + off);   off += (size_t)N * 4;
  off = (off + 15) & ~(size_t)15;
  double* pd   = (double*)(ws + off); off += (size_t)N * 8;
  double* pw   = (double*)(ws + off); off += (size_t)NWC_BLOCKS * 8;

  k_zero<<<16, 256, 0, stream>>>(rowsum);
  k_normalize<<<N, 256, 0, stream>>>(s_emb, snorm, rsq_s);
  k_normalize<<<N, 256, 0, stream>>>(t_emb, tnorm, rsq_t);
  dim3 gg(N / 128, N / 128);
  k_gram<0><<<gg, 256, 0, stream>>>(snorm, rsq_s, Gs, rowsum);
  k_gram<1><<<gg, 256, 0, stream>>>(tnorm, rsq_t, Gt, nullptr);
  k_mean<<<16, 256, 0, stream>>>(rowsum, mean);
  k_rowpass<<<N, 256, 0, stream>>>(Gs, Gt, ids, mean, topk, pd);
  k_buildV<<<N / 256, 256, 0, stream>>>(topk, L, cnt);
  k_wc<<<NWC_BLOCKS, 256, 0, stream>>>(topk, L, cnt, Gs, mean, pw);
  k_final<<<1, 256, 0, stream>>>(pd, pw, out);
}

// Round 4
// 234.699 us; speedup vs baseline: 4.0667x; 1.2527x over previous
//
#include <hip/hip_runtime.h>
#include <math.h>

#define N 4096
#define D 512
#define TOPK 10
#define TOPK_HALF 5
#define WC_BLOCKS (N * TOPK_HALF / 4)   // one wave per (i,m) task, 4 waves/block

typedef __bf16 bf16;
typedef __bf16 bf16x8 __attribute__((ext_vector_type(8)));
typedef float f32x4 __attribute__((ext_vector_type(4)));
typedef unsigned long long u64;

__device__ __forceinline__ void gl_lds16(const void* g, void* l) {
  __builtin_amdgcn_global_load_lds(
      (const __attribute__((address_space(1))) void*)g,
      (__attribute__((address_space(3))) void*)l, 16, 0, 0);
}

// ---------------- zero rowsum ----------------
__global__ void k_zero(float* rowsum) {
  int i = blockIdx.x * 256 + threadIdx.x;
  if (i < N) rowsum[i] = 0.f;
}

// ---------------- K0: L2-normalize -> bf16 rows + rsq of bf16 values ----------------
__global__ __launch_bounds__(256) void k_normalize(const float* __restrict__ x,
                                                   bf16* __restrict__ y,
                                                   float* __restrict__ rowsq) {
  int row = blockIdx.x, tid = threadIdx.x;
  const float* xr = x + (size_t)row * D;
  float v0 = xr[tid], v1 = xr[tid + 256];
  float ss = v0 * v0 + v1 * v1;
  __shared__ float red[4];
  for (int off = 32; off > 0; off >>= 1) ss += __shfl_down(ss, off, 64);
  if ((tid & 63) == 0) red[tid >> 6] = ss;
  __syncthreads();
  float tot = red[0] + red[1] + red[2] + red[3];
  float inv = 1.0f / fmaxf(sqrtf(tot), 1e-12f);
  bf16 b0 = (bf16)(v0 * inv), b1 = (bf16)(v1 * inv);
  bf16* yr = y + (size_t)row * D;
  yr[tid] = b0; yr[tid + 256] = b1;
  float f0 = (float)b0, f1 = (float)b1;
  float s2 = f0 * f0 + f1 * f1;
  for (int off = 32; off > 0; off >>= 1) s2 += __shfl_down(s2, off, 64);
  __syncthreads();
  if ((tid & 63) == 0) red[tid >> 6] = s2;
  __syncthreads();
  if (tid == 0) rowsq[row] = red[0] + red[1] + red[2] + red[3];
}

// ---------------- K1: MFMA bf16 Gram, fused epilogue ----------------
// MODE 0: G = sqrt(max(rsq_i+rsq_j-2*dot,0))  (raw S_dist) + rowsum atomics
// MODE 1: G = exp(-max(sq,0))                 (W_P)
template <int MODE>
__global__ __launch_bounds__(256) void k_gram(const bf16* __restrict__ Y,
                                              const float* __restrict__ rsq,
                                              float* __restrict__ G,
                                              float* __restrict__ rowsum) {
  __shared__ bf16 As[128 * 32];
  __shared__ bf16 Bs[128 * 32];
  int bx = blockIdx.x, by = blockIdx.y;
  int tid = threadIdx.x;
  int lane = tid & 63, w = tid >> 6;
  int wr = w >> 1, wc = w & 1;
  f32x4 acc[4][4] = {};

  const char* Abase = (const char*)(Y + (size_t)(by * 128) * D);
  const char* Bbase = (const char*)(Y + (size_t)(bx * 128) * D);
  int c0 = tid, c1 = tid + 256;
  int r0 = c0 >> 2, q0 = c0 & 3;
  int r1 = c1 >> 2, q1 = c1 & 3;
  bf16* lA0 = As + (size_t)(w * 64) * 8;
  bf16* lA1 = As + (size_t)(256 + w * 64) * 8;
  bf16* lB0 = Bs + (size_t)(w * 64) * 8;
  bf16* lB1 = Bs + (size_t)(256 + w * 64) * 8;

  int arow = wr * 64 + (lane & 15);
  int brow = wc * 64 + (lane & 15);
  int kq = (lane >> 4) * 8;

  for (int k0 = 0; k0 < D; k0 += 32) {
    size_t off0 = (size_t)r0 * (D * 2) + (size_t)k0 * 2 + q0 * 16;
    size_t off1 = (size_t)r1 * (D * 2) + (size_t)k0 * 2 + q1 * 16;
    gl_lds16(Abase + off0, lA0);
    gl_lds16(Abase + off1, lA1);
    gl_lds16(Bbase + off0, lB0);
    gl_lds16(Bbase + off1, lB1);
    __syncthreads();
    bf16x8 af[4], bfr[4];
#pragma unroll
    for (int u = 0; u < 4; ++u) af[u] = *(bf16x8*)&As[(arow + u * 16) * 32 + kq];
#pragma unroll
    for (int v = 0; v < 4; ++v) bfr[v] = *(bf16x8*)&Bs[(brow + v * 16) * 32 + kq];
#pragma unroll
    for (int u = 0; u < 4; ++u)
#pragma unroll
      for (int v = 0; v < 4; ++v)
        acc[u][v] = __builtin_amdgcn_mfma_f32_16x16x32_bf16(af[u], bfr[v], acc[u][v], 0, 0, 0);
    __syncthreads();
  }

  int colb = bx * 128 + wc * 64 + (lane & 15);
  int rowb = by * 128 + wr * 64 + ((lane >> 4) << 2);
  float rsc[4];
#pragma unroll
  for (int v = 0; v < 4; ++v) rsc[v] = rsq[colb + v * 16];
#pragma unroll
  for (int u = 0; u < 4; ++u) {
    float rsr[4];
#pragma unroll
    for (int reg = 0; reg < 4; ++reg) rsr[reg] = rsq[rowb + u * 16 + reg];
    float rpart[4] = {0.f, 0.f, 0.f, 0.f};
#pragma unroll
    for (int v = 0; v < 4; ++v) {
      f32x4 a = acc[u][v];
#pragma unroll
      for (int reg = 0; reg < 4; ++reg) {
        float sq = fmaxf(rsr[reg] + rsc[v] - 2.0f * a[reg], 0.0f);
        float val = (MODE == 0) ? sqrtf(sq) : expf(-sq);
        G[(size_t)(rowb + u * 16 + reg) * N + colb + v * 16] = val;
        if (MODE == 0) rpart[reg] += val;
      }
    }
    if (MODE == 0) {
#pragma unroll
      for (int reg = 0; reg < 4; ++reg) {
        float s = rpart[reg];
        s += __shfl_xor(s, 1, 64);
        s += __shfl_xor(s, 2, 64);
        s += __shfl_xor(s, 4, 64);
        s += __shfl_xor(s, 8, 64);
        if ((lane & 15) == 0) atomicAdd(&rowsum[rowb + u * 16 + reg], s);
      }
    }
  }
}

// ---------------- K2: mean = rowsum / N ----------------
__global__ void k_mean(const float* __restrict__ rowsum, float* __restrict__ mean) {
  int i = blockIdx.x * 256 + threadIdx.x;
  if (i < N) mean[i] = rowsum[i] * (1.0f / (float)N);
}

// ---------------- K3: fused row pass: exact top-10 + dense loss partial ----------------
__global__ __launch_bounds__(256) void k_rowpass(const float* __restrict__ Gs,
                                                 const float* __restrict__ Wp,
                                                 const int* __restrict__ ids,
                                                 const float* __restrict__ mean,
                                                 int* __restrict__ topk,
                                                 double* __restrict__ pd) {
  __shared__ u64 lds[256 * TOPK];  // 20 KB
  __shared__ double dred[4];
  int i = blockIdx.x, tid = threadIdx.x;
  int idi = ids[i];
  float invm = 1.0f / mean[i];
  const float* wrow = Wp + (size_t)i * N;
  const float* srow = Gs + (size_t)i * N;
  u64 top[TOPK];
#pragma unroll
  for (int o = 0; o < TOPK; ++o) top[o] = 0ULL;
  float dsum = 0.f;
#pragma unroll
  for (int s = 0; s < 4; ++s) {
    int j0 = s * 1024 + tid * 4;
    float4 w4 = *(const float4*)(wrow + j0);
    float4 g4 = *(const float4*)(srow + j0);
    const float* wv = (const float*)&w4;
    const float* gv = (const float*)&g4;
#pragma unroll
    for (int u = 0; u < 4; ++u) {
      int j = j0 + u;
      float wkey = (ids[j] == idi) ? 1.0f : wv[u];
      u64 key = ((u64)__float_as_uint(wkey) << 32) |
                (u64)(0xFFFFFFFFu - (unsigned)j);  // val desc, idx asc
      if (key > top[TOPK - 1]) {
        top[TOPK - 1] = key;
#pragma unroll
        for (int a = TOPK - 2; a >= 0; --a) {
          if (top[a + 1] > top[a]) { u64 t = top[a]; top[a] = top[a + 1]; top[a + 1] = t; }
        }
      }
      if (j != i) {
        float sd = gv[u] * invm;
        float r = fmaxf(1.0f - sd, 0.0f); r *= r;
        dsum += r + 0.5f * wv[u] * (sd * sd - r);
      }
    }
  }
  double dl = (double)dsum;
  for (int off = 32; off > 0; off >>= 1) dl += __shfl_down(dl, off, 64);
  if ((tid & 63) == 0) dred[tid >> 6] = dl;
#pragma unroll
  for (int o = 0; o < TOPK; ++o) lds[tid * TOPK + o] = top[o];
  __syncthreads();
  for (int off = 128; off >= 1; off >>= 1) {
    if (tid < off) {
      u64 out[TOPK];
      int pa = 0, pb = 0;
#pragma unroll
      for (int o = 0; o < TOPK; ++o) {
        u64 ka = (pa < TOPK) ? lds[tid * TOPK + pa] : 0ULL;
        u64 kb = (pb < TOPK) ? lds[(tid + off) * TOPK + pb] : 0ULL;
        bool ta = ka >= kb;
        out[o] = ta ? ka : kb;
        pa += ta ? 1 : 0;
        pb += ta ? 0 : 1;
      }
#pragma unroll
      for (int o = 0; o < TOPK; ++o) lds[tid * TOPK + o] = out[o];
    }
    __syncthreads();
  }
  if (tid == 0) {
#pragma unroll
    for (int o = 0; o < TOPK; ++o)
      topk[i * TOPK + o] = (int)(0xFFFFFFFFu - (unsigned)(lds[o] & 0xFFFFFFFFu));
    pd[i] = dred[0] + dred[1] + dred[2] + dred[3];
  }
}

// ---------------- K4: mutual-kNN lists ----------------
__global__ void k_buildV(const int* __restrict__ topk, int* __restrict__ L,
                         int* __restrict__ cnt) {
  int i = blockIdx.x * 256 + threadIdx.x;
  if (i >= N) return;
  int c = 0;
  for (int r = 0; r < TOPK; ++r) {
    int j = topk[i * TOPK + r];
    bool mut = false;
    for (int q = 0; q < TOPK; ++q) mut |= (topk[j * TOPK + q] == i);
    if (mut) L[i * TOPK + c++] = j;
  }
  cnt[i] = c;
}

// ---------------- K5: sparse W_C loss, one wave per (i,m) task ----------------
__global__ __launch_bounds__(256) void k_wc(const int* __restrict__ topk,
                                            const int* __restrict__ L,
                                            const int* __restrict__ cnt,
                                            const float* __restrict__ Gs,
                                            const float* __restrict__ mean,
                                            double* __restrict__ pw) {
  int tid = threadIdx.x;
  int lane = tid & 63;
  int wv = tid >> 6;
  int task = blockIdx.x * 4 + wv;            // always < N*TOPK_HALF
  int i = task / TOPK_HALF, m = task % TOPK_HALF;
  int r = topk[i * TOPK + m];
  int cr = cnt[r];
  double local = 0.0;
  if (cr > 0) {
    float denom = (float)(cr > 1 ? cr : 1);
    int lval = (lane < cr) ? L[r * TOPK + lane] : -1;
    int Lr[TOPK];
#pragma unroll
    for (int a = 0; a < TOPK; ++a) Lr[a] = __shfl(lval, a, 64);
    float invmi = 1.0f / mean[i];
    // lane-parallel gathers: lane jj holds neighbor j = L_r[jj]
    int cj_l = 0; float sr_l = 0.f, mj_l = 1.0f;
    if (lane < cr) {
      cj_l = cnt[lval];
      sr_l = Gs[(size_t)i * N + lval];
      mj_l = mean[lval];
    }
    for (int jj = 0; jj < cr; ++jj) {
      int j = Lr[jj];
      if (j == i) continue;
      int cj = __shfl(cj_l, jj, 64);
      float sr = __shfl(sr_l, jj, 64);
      float mj = __shfl(mj_l, jj, 64);
      int ljb = (lane < cj) ? L[j * TOPK + lane] : -1;
      int match = 0;
#pragma unroll
      for (int a = 0; a < TOPK; ++a) match |= ((a < cr) && (ljb == Lr[a])) ? 1 : 0;
      int vv = __popcll(__ballot(match != 0));
      float wgt = (float)vv / denom;
      float sdij = sr * invmi;
      float sdji = sr / mj;
      float Rij = fmaxf(1.0f - sdij, 0.0f); Rij *= Rij;
      float Rji = fmaxf(1.0f - sdji, 0.0f); Rji *= Rji;
      float Fij = sdij * sdij - Rij;
      float Fji = sdji * sdji - Rji;
      local += (double)(wgt * (Fij + Fji));
    }
    local *= (1.0 / 20.0);
  }
  __shared__ double red[4];
  if (lane == 0) red[wv] = local;
  __syncthreads();
  if (tid == 0) pw[blockIdx.x] = red[0] + red[1] + red[2] + red[3];
}

// ---------------- K6: final reduce ----------------
__global__ __launch_bounds__(256) void k_final(const double* __restrict__ pd,
                                               const double* __restrict__ pw,
                                               float* __restrict__ out) {
  int tid = threadIdx.x;
  double s = 0.0;
  for (int i = tid; i < N; i += 256) s += pd[i];
  for (int i = tid; i < WC_BLOCKS; i += 256) s += pw[i];
  for (int off = 32; off > 0; off >>= 1) s += __shfl_down(s, off, 64);
  __shared__ double red[4];
  if ((tid & 63) == 0) red[tid >> 6] = s;
  __syncthreads();
  if (tid == 0)
    out[0] = (float)((red[0] + red[1] + red[2] + red[3]) /
                     ((double)N * (double)(N - 1)));
}

extern "C" void kernel_launch(void* const* d_in, const int* in_sizes, int n_in,
                              void* d_out, int out_size, void* d_ws, size_t ws_size,
                              hipStream_t stream) {
  const float* s_emb = (const float*)d_in[0];
  const float* t_emb = (const float*)d_in[1];
  const int* ids = (const int*)d_in[2];
  float* out = (float*)d_out;

  char* ws = (char*)d_ws;
  size_t off = 0;
  bf16* snorm = (bf16*)(ws + off); off += (size_t)N * D * 2;        // 4 MB
  bf16* tnorm = (bf16*)(ws + off); off += (size_t)N * D * 2;        // 4 MB
  float* Gs    = (float*)(ws + off); off += (size_t)N * N * 4;      // 64 MB
  float* Gt    = (float*)(ws + off); off += (size_t)N * N * 4;      // 64 MB
  float* rsq_s = (float*)(ws + off); off += (size_t)N * 4;
  float* rsq_t = (float*)(ws + off); off += (size_t)N * 4;
  float* rowsum= (float*)(ws + off); off += (size_t)N * 4;
  float* mean  = (float*)(ws + off); off += (size_t)N * 4;
  int*   topk  = (int*)(ws + off);   off += (size_t)N * TOPK * 4;
  int*   L     = (int*)(ws + off);   off += (size_t)N * TOPK * 4;
  int*   cnt   = (int*)(ws + off);   off += (size_t)N * 4;
  off = (off + 15) & ~(size_t)15;
  double* pd   = (double*)(ws + off); off += (size_t)N * 8;
  double* pw   = (double*)(ws + off); off += (size_t)WC_BLOCKS * 8;

  k_zero<<<16, 256, 0, stream>>>(rowsum);
  k_normalize<<<N, 256, 0, stream>>>(s_emb, snorm, rsq_s);
  k_normalize<<<N, 256, 0, stream>>>(t_emb, tnorm, rsq_t);
  dim3 gg(N / 128, N / 128);
  k_gram<0><<<gg, 256, 0, stream>>>(snorm, rsq_s, Gs, rowsum);
  k_gram<1><<<gg, 256, 0, stream>>>(tnorm, rsq_t, Gt, nullptr);
  k_mean<<<16, 256, 0, stream>>>(rowsum, mean);
  k_rowpass<<<N, 256, 0, stream>>>(Gs, Gt, ids, mean, topk, pd);
  k_buildV<<<N / 256, 256, 0, stream>>>(topk, L, cnt);
  k_wc<<<WC_BLOCKS, 256, 0, stream>>>(topk, L, cnt, Gs, mean, pw);
  k_final<<<1, 256, 0, stream>>>(pd, pw, out);
}